// Round 6
// baseline (2212.376 us; speedup 1.0000x reference)
//
#include <hip/hip_runtime.h>

namespace {

constexpr int N_NODES = 2048;
constexpr int IN_DIM  = 256;
constexpr int HEADS   = 6;
constexpr int HD      = 64;
constexpr int OUT_DIM = HEADS * HD;   // 384

// ---------------------------------------------------------------------------
// Kernel 1: projections + attention-vector dots.
// grid (512, 6, 2), block 256 = 4 waves; wave w handles node blockIdx.x*4+w.
// All 4 waves stream the same W (L1 reuse). f = lane.
// ---------------------------------------------------------------------------
__global__ __launch_bounds__(256) void qk_proj(
    const float* __restrict__ hmat, const float* __restrict__ Wsrc,
    const float* __restrict__ Wdst, const float* __restrict__ a,
    float* __restrict__ Qw, float* __restrict__ Kw,
    float* __restrict__ qaw, float* __restrict__ kaw)
{
  const int lane = threadIdx.x & 63;
  const int w    = threadIdx.x >> 6;
  const int i    = blockIdx.x * 4 + w;
  const int head = blockIdx.y;
  const int z    = blockIdx.z;
  const float* __restrict__ W = (z ? Wdst : Wsrc) + (size_t)head * IN_DIM * HD;
  const float* __restrict__ hrow = hmat + (size_t)i * IN_DIM;

  float a0 = 0.f, a1 = 0.f, a2 = 0.f, a3 = 0.f;
  #pragma unroll 4
  for (int k = 0; k < IN_DIM; k += 4) {
    const float4 hv = *(const float4*)&hrow[k];
    a0 = fmaf(hv.x, W[(k + 0) * HD + lane], a0);
    a1 = fmaf(hv.y, W[(k + 1) * HD + lane], a1);
    a2 = fmaf(hv.z, W[(k + 2) * HD + lane], a2);
    a3 = fmaf(hv.w, W[(k + 3) * HD + lane], a3);
  }
  const float acc = (a0 + a1) + (a2 + a3);
  (z ? Kw : Qw)[((size_t)head * N_NODES + i) * HD + lane] = acc;

  float rsum = acc * a[head * HD + lane];
  #pragma unroll
  for (int off = 32; off; off >>= 1) rsum += __shfl_xor(rsum, off);
  if (lane == 0) (z ? kaw : qaw)[head * N_NODES + i] = 0.6f * rsum;
}

// ---------------------------------------------------------------------------
// Kernel 2: fused scores + masked softmax + attn_mean + PV + h'.
// grid 256 x 512 threads (8 waves -> 2 waves/SIMD). Block owns 8 rows.
//  - adj staged ONCE as a ballot bitmask (2 KB).
//  - pass1: thread owns j-pairs {2t, 2t+1} (+1024); K rows streamed from
//    global into registers (each 128B line read exactly once per block/head);
//    Q via uniform-address b128 LDS broadcasts (conflict-free).
//    e written to e_lds[8][2048]; per-row max in regs -> 2-level reduce.
//  - pass2a: exp(e-m) in-place (own slots) + row sums -> invs.
//  - attn: own slots, scale by invs, RMW on global out_attn across heads.
//  - PV: wave r = t>>6 handles row r; lanes = 16 f-quads x 4 j-splits;
//    p by LDS broadcast, K from global (L1-shared across the 8 waves).
// ---------------------------------------------------------------------------
__global__ __launch_bounds__(512, 2) void gat_fused(
    const float* __restrict__ Qw, const float* __restrict__ Kw,
    const float* __restrict__ qaw, const float* __restrict__ kaw,
    const float* __restrict__ a, const float* __restrict__ adj,
    const float* __restrict__ bias, float* __restrict__ out_h,
    float* __restrict__ out_attn)
{
  __shared__ float e_lds[8][N_NODES];             // 64 KB
  __shared__ float Qs[8][64];                     // 2 KB
  __shared__ float a04[64];
  __shared__ float qas[8];
  __shared__ float msh[8], invs[8];
  __shared__ float red[8][8];                     // [row][wave]
  __shared__ unsigned long long mask_lds[8][32];  // 2 KB adjacency bitmask

  const int t    = threadIdx.x;
  const int lane = t & 63;
  const int wv   = t >> 6;       // 0..7
  const int i0   = blockIdx.x * 8;

  // ---- adjacency bitmask, once per block: wave wv owns row wv ----
  for (int c = 0; c < 32; ++c) {
    const float ad = adj[(size_t)(i0 + wv) * N_NODES + c * 64 + lane];
    const unsigned long long b = __ballot(ad > 0.f);
    if (lane == 0) mask_lds[wv][c] = b;
  }

  for (int hh = 0; hh < HEADS; ++hh) {
    __syncthreads();   // prev head done with e_lds/Qs (also covers mask stage)
    Qs[t >> 6][t & 63] = Qw[((size_t)hh * N_NODES + i0 + (t >> 6)) * HD + (t & 63)];
    if (t < 64) a04[t] = 0.4f * a[hh * HD + t];
    if (t < 8)  qas[t] = qaw[hh * N_NODES + i0 + t];
    __syncthreads();

    // ================= pass 1: e + per-row running max =================
    float m[8];
    #pragma unroll
    for (int r = 0; r < 8; ++r) m[r] = -3e38f;

    for (int jp = 0; jp < 2; ++jp) {
      const int j0 = 2 * t + jp * 1024;       // thread's j-pair
      const float* __restrict__ Kp = Kw + ((size_t)hh * N_NODES + j0) * HD;
      float acc[8][2] = {};
      #pragma unroll
      for (int fcb = 0; fcb < 2; ++fcb) {     // f-halves of 32
        #pragma unroll
        for (int fc = 0; fc < 8; ++fc) {      // 4-float steps
          const int f = fcb * 32 + fc * 4;
          const float4 kva = *(const float4*)&Kp[f];        // row j0
          const float4 kvb = *(const float4*)&Kp[64 + f];   // row j0+1
          const float4 av  = *(const float4*)&a04[f];       // broadcast
          #pragma unroll
          for (int r = 0; r < 8; ++r) {
            const float4 qv = *(const float4*)&Qs[r][f];    // broadcast
            acc[r][0] = fmaf(fabsf(qv.x + kva.x), av.x, acc[r][0]);
            acc[r][0] = fmaf(fabsf(qv.y + kva.y), av.y, acc[r][0]);
            acc[r][0] = fmaf(fabsf(qv.z + kva.z), av.z, acc[r][0]);
            acc[r][0] = fmaf(fabsf(qv.w + kva.w), av.w, acc[r][0]);
            acc[r][1] = fmaf(fabsf(qv.x + kvb.x), av.x, acc[r][1]);
            acc[r][1] = fmaf(fabsf(qv.y + kvb.y), av.y, acc[r][1]);
            acc[r][1] = fmaf(fabsf(qv.z + kvb.z), av.z, acc[r][1]);
            acc[r][1] = fmaf(fabsf(qv.w + kvb.w), av.w, acc[r][1]);
          }
        }
      }
      // finalize pair: +qa +ka, mask, store, max-track
      const float2 kaj = *(const float2*)&kaw[hh * N_NODES + j0];
      const int c = j0 >> 6;                   // 0..31
      const int b0 = j0 & 63, b1 = b0 + 1;
      #pragma unroll
      for (int r = 0; r < 8; ++r) {
        const unsigned long long mw = mask_lds[r][c];
        const float e0 = ((mw >> b0) & 1ull) ? acc[r][0] + qas[r] + kaj.x : -1e30f;
        const float e1 = ((mw >> b1) & 1ull) ? acc[r][1] + qas[r] + kaj.y : -1e30f;
        *(float2*)&e_lds[r][j0] = make_float2(e0, e1);
        m[r] = fmaxf(m[r], fmaxf(e0, e1));
      }
    }
    // reduce max: wave butterfly then cross-wave via red
    #pragma unroll
    for (int r = 0; r < 8; ++r) {
      float v = m[r];
      #pragma unroll
      for (int off = 32; off; off >>= 1) v = fmaxf(v, __shfl_xor(v, off));
      if (lane == 0) red[r][wv] = v;
    }
    __syncthreads();
    if (t < 8) {
      float v = red[t][0];
      #pragma unroll
      for (int q = 1; q < 8; ++q) v = fmaxf(v, red[t][q]);
      msh[t] = v;
    }
    __syncthreads();

    // ================= pass 2a: exp in place + row sums =================
    float s[8];
    #pragma unroll
    for (int r = 0; r < 8; ++r) s[r] = 0.f;
    #pragma unroll
    for (int jp = 0; jp < 2; ++jp) {
      const int j0 = 2 * t + jp * 1024;
      #pragma unroll
      for (int r = 0; r < 8; ++r) {
        const float2 v = *(const float2*)&e_lds[r][j0];
        const float mr = msh[r];
        const float p0 = __expf(v.x - mr);
        const float p1 = __expf(v.y - mr);
        *(float2*)&e_lds[r][j0] = make_float2(p0, p1);
        s[r] += p0 + p1;
      }
    }
    #pragma unroll
    for (int r = 0; r < 8; ++r) {
      float v = s[r];
      #pragma unroll
      for (int off = 32; off; off >>= 1) v += __shfl_xor(v, off);
      if (lane == 0) red[r][wv] = v;
    }
    __syncthreads();
    if (t < 8) {
      float v = red[t][0];
      #pragma unroll
      for (int q = 1; q < 8; ++q) v += red[t][q];
      invs[t] = 1.0f / v;
    }
    __syncthreads();

    // ================= attn_mean RMW (own slots) =================
    #pragma unroll
    for (int jp = 0; jp < 2; ++jp) {
      const int j0 = 2 * t + jp * 1024;
      #pragma unroll
      for (int r = 0; r < 8; ++r) {
        const float2 v = *(const float2*)&e_lds[r][j0];
        const float iv = invs[r];
        float2 p = make_float2(v.x * iv, v.y * iv);
        float2* ap = (float2*)&out_attn[(size_t)(i0 + r) * N_NODES + j0];
        if (hh == 0) {
          *ap = p;
        } else if (hh == HEADS - 1) {
          const float2 po = *ap;
          *ap = make_float2((po.x + p.x) * (1.0f / 6.0f),
                            (po.y + p.y) * (1.0f / 6.0f));
        } else {
          const float2 po = *ap;
          *ap = make_float2(po.x + p.x, po.y + p.y);
        }
      }
    }

    // ================= PV: wave r, lanes = 16 fq x 4 js =================
    {
      const int r  = wv;
      const int fq = t & 15;
      const int js = (t >> 4) & 3;
      const float* __restrict__ Kp =
          Kw + ((size_t)hh * N_NODES + js * 512) * HD + fq * 4;
      const float* __restrict__ pp = &e_lds[r][js * 512];
      float4 acc = make_float4(0.f, 0.f, 0.f, 0.f);
      for (int j = 0; j < 512; j += 8) {
        #pragma unroll
        for (int u = 0; u < 8; ++u) {
          const float p = pp[j + u];
          const float4 kv = *(const float4*)&Kp[(size_t)(j + u) * HD];
          acc.x = fmaf(p, kv.x, acc.x);
          acc.y = fmaf(p, kv.y, acc.y);
          acc.z = fmaf(p, kv.z, acc.z);
          acc.w = fmaf(p, kv.w, acc.w);
        }
      }
      acc.x += __shfl_xor(acc.x, 16); acc.x += __shfl_xor(acc.x, 32);
      acc.y += __shfl_xor(acc.y, 16); acc.y += __shfl_xor(acc.y, 32);
      acc.z += __shfl_xor(acc.z, 16); acc.z += __shfl_xor(acc.z, 32);
      acc.w += __shfl_xor(acc.w, 16); acc.w += __shfl_xor(acc.w, 32);
      if ((t & 63) < 16) {
        const float iv = invs[r];
        const float4 bv = *(const float4*)&bias[hh * 64 + fq * 4];
        float4 o;
        o.x = acc.x * iv + bv.x;
        o.y = acc.y * iv + bv.y;
        o.z = acc.z * iv + bv.z;
        o.w = acc.w * iv + bv.w;
        *(float4*)&out_h[(size_t)(i0 + r) * OUT_DIM + hh * 64 + fq * 4] = o;
      }
    }
  }
}

}  // namespace

// ---------------------------------------------------------------------------
extern "C" void kernel_launch(void* const* d_in, const int* in_sizes, int n_in,
                              void* d_out, int out_size, void* d_ws, size_t ws_size,
                              hipStream_t stream) {
  const float* hmat = (const float*)d_in[0];
  const float* adj  = (const float*)d_in[1];
  const float* Wsrc = (const float*)d_in[2];
  const float* Wdst = (const float*)d_in[3];
  const float* a    = (const float*)d_in[4];
  const float* bias = (const float*)d_in[5];

  float* out_h    = (float*)d_out;                        // 2048 x 384
  float* out_attn = out_h + (size_t)N_NODES * OUT_DIM;    // 2048 x 2048

  float* Qw  = (float*)d_ws;                              // [6][2048][64]
  float* Kw  = Qw + (size_t)HEADS * N_NODES * HD;         // [6][2048][64]
  float* qaw = Kw + (size_t)HEADS * N_NODES * HD;         // [6][2048]
  float* kaw = qaw + HEADS * N_NODES;                     // [6][2048]

  qk_proj<<<dim3(N_NODES / 4, HEADS, 2), 256, 0, stream>>>(hmat, Wsrc, Wdst, a,
                                                           Qw, Kw, qaw, kaw);
  gat_fused<<<dim3(N_NODES / 8), 512, 0, stream>>>(Qw, Kw, qaw, kaw, a, adj,
                                                   bias, out_h, out_attn);
}